// Round 1
// baseline (313.092 us; speedup 1.0000x reference)
//
#include <hip/hip_runtime.h>
#include <hip/hip_bf16.h>

#define OUT_CH 4096
#define IN_FEAT 11008
#define NVEC (IN_FEAT / 4)   // 2752 float4 per row
#define EPS 1e-5f
#define BIT_BOUND 6.0f

// Native clang vector type — accepted by __builtin_nontemporal_store
// (HIP's float4 is a struct and is rejected).
typedef float fvec4 __attribute__((ext_vector_type(4)));

// One block per output channel (row). Row scalars computed once per block.
//
// v2 changes vs v1 (294-297 us session best):
//  - ALL 11 row loads issued up-front (was 8 -> store -> 2 -> store -> 1):
//    removes the issue bubbles between load batches; tail lanes load a safe
//    duplicate vec4 branchlessly so the load stream has no divergence
//    (stores of the tail remain predicated).
//  - loads are regular cached loads (nt dropped): pure-stream read, nt bought
//    nothing and marks lines evict-first; stores keep nt (out has no reuse,
//    and leaving 180 MB dirty in LLC ahead of the harness re-poison fill is
//    pure cost).
//  - __launch_bounds__(256, 4): guarantee >=4 waves/EU (16 waves/CU) so a
//    VGPR creep past 64 can't halve occupancy. 11 vec4 in flight = 44 data
//    VGPRs + addressing ~= 60, well under the 128 cap this implies.
__global__ __launch_bounds__(256, 4) void fake_quant_kernel(
    const float* __restrict__ weight,
    const float* __restrict__ alh,
    const float* __restrict__ bit,
    float* __restrict__ out)
{
    const int row = blockIdx.x;
    const int tid = threadIdx.x;

    const fvec4* __restrict__ wrow =
        (const fvec4*)(weight + (size_t)row * IN_FEAT);
    fvec4* __restrict__ orow = (fvec4*)(out + (size_t)row * IN_FEAT);

    // Issue all loads first: 10 full batches of 256 (2560 vec4) + 192 tail.
    fvec4 w[11];
    #pragma unroll
    for (int j = 0; j < 10; ++j)
        w[j] = wrow[tid + j * 256];
    const bool has_tail = tid < (NVEC - 2560);          // 192 lanes
    const int tail_idx = has_tail ? (tid + 2560) : (NVEC - 1);
    w[10] = wrow[tail_idx];

    // Per-row quant params (forward values; STE affects only gradients).
    // alh/bit addresses are wave-uniform -> compiler emits s_load; these
    // overlap with the vector loads above.
    const float s = fmaxf(alh[row], EPS);
    const float b_eff = fminf(fmaxf(fabsf(bit[row]), 1.0f), BIT_BOUND);
    const float b_r = rintf(b_eff);                      // jnp.round = half-to-even
    const float qmax = fmaxf(exp2f(b_r - 1.0f) - 1.0f, 1.0f);
    const float qmin = -qmax;

    // Exact IEEE division (matches np w/scale bit-exactly; rintf = half-even).
    auto q4 = [&](fvec4 v) -> fvec4 {
        fvec4 r;
        r.x = fminf(fmaxf(rintf(v.x / s), qmin), qmax) * s;
        r.y = fminf(fmaxf(rintf(v.y / s), qmin), qmax) * s;
        r.z = fminf(fmaxf(rintf(v.z / s), qmin), qmax) * s;
        r.w = fminf(fmaxf(rintf(v.w / s), qmin), qmax) * s;
        return r;
    };

    #pragma unroll
    for (int j = 0; j < 10; ++j)
        __builtin_nontemporal_store(q4(w[j]), &orow[tid + j * 256]);
    if (has_tail)
        __builtin_nontemporal_store(q4(w[10]), &orow[tid + 2560]);
}

extern "C" void kernel_launch(void* const* d_in, const int* in_sizes, int n_in,
                              void* d_out, int out_size, void* d_ws, size_t ws_size,
                              hipStream_t stream) {
    const float* weight = (const float*)d_in[0];
    const float* alh    = (const float*)d_in[1];
    const float* bit    = (const float*)d_in[2];
    // d_in[3] = init_weight_bit (unused in forward at init)
    float* out = (float*)d_out;

    fake_quant_kernel<<<OUT_CH, 256, 0, stream>>>(weight, alh, bit, out);
}

// Round 2
// 300.312 us; speedup vs baseline: 1.0426x; 1.0426x over previous
//
#include <hip/hip_runtime.h>
#include <hip/hip_bf16.h>

#define OUT_CH 4096
#define IN_FEAT 11008
#define NVEC (IN_FEAT / 4)   // 2752 float4 per row
#define EPS 1e-5f
#define BIT_BOUND 6.0f

// Native clang vector type — accepted by __builtin_nontemporal_load
// (HIP's float4 is a struct and is rejected).
typedef float fvec4 __attribute__((ext_vector_type(4)));

// One block per output channel (row). Row scalars computed once per block.
//
// v3 = v1 (proven 294-297 us) with ONE change: stores are regular cached
// stores instead of nontemporal.
//   Mechanism: the two streams that measure ~6.3-6.5 TB/s on this chip
//   (m13 float4 copy, rocclr fillBuffer) both use cached stores — writes
//   allocate in L2 and reach HBM as batched full-line evictions. nt stores
//   bypass L2 and expose the store stream to HBM write latency/turnaround;
//   v1's kernel ran at only ~4.7 TB/s. The "don't dirty LLC before the
//   re-poison fill" argument is void: the fill overwrites the same
//   addresses, so dirty lines are updated in place (fills measured
//   unchanged across v1/v2 supports this).
// Loads KEEP nt (no reuse; v2 weakly suggests cached loads hurt).
// Load schedule unchanged from v1: 8-deep batch, then 2, then 192-lane tail.
__global__ __launch_bounds__(256) void fake_quant_kernel(
    const float* __restrict__ weight,
    const float* __restrict__ alh,
    const float* __restrict__ bit,
    float* __restrict__ out)
{
    const int row = blockIdx.x;

    // Per-row quant params (forward values; STE affects only gradients).
    const float s = fmaxf(alh[row], EPS);
    const float b_eff = fminf(fmaxf(fabsf(bit[row]), 1.0f), BIT_BOUND);
    const float b_r = rintf(b_eff);                        // jnp.round = half-to-even
    const float qmax = fmaxf(exp2f(b_r - 1.0f) - 1.0f, 1.0f);
    const float qmin = -qmax;

    const fvec4* __restrict__ wrow =
        (const fvec4*)(weight + (size_t)row * IN_FEAT);
    fvec4* __restrict__ orow = (fvec4*)(out + (size_t)row * IN_FEAT);
    const int tid = threadIdx.x;

    // Exact IEEE division (matches np w/scale bit-exactly; rintf = half-even).
    auto q4 = [&](fvec4 w) -> fvec4 {
        fvec4 r;
        r.x = fminf(fmaxf(rintf(w.x / s), qmin), qmax) * s;
        r.y = fminf(fmaxf(rintf(w.y / s), qmin), qmax) * s;
        r.z = fminf(fmaxf(rintf(w.z / s), qmin), qmax) * s;
        r.w = fminf(fmaxf(rintf(w.w / s), qmin), qmax) * s;
        return r;
    };

    // Batch of 8: indices tid + {0..7}*256
    {
        fvec4 w[8];
        #pragma unroll
        for (int j = 0; j < 8; ++j)
            w[j] = __builtin_nontemporal_load(&wrow[tid + j * 256]);
        #pragma unroll
        for (int j = 0; j < 8; ++j)
            orow[tid + j * 256] = q4(w[j]);
    }
    // Remainder: 2752 - 2048 = 704 = 2*256 + 192
    {
        fvec4 w0 = __builtin_nontemporal_load(&wrow[tid + 2048]);
        fvec4 w1 = __builtin_nontemporal_load(&wrow[tid + 2304]);
        orow[tid + 2048] = q4(w0);
        orow[tid + 2304] = q4(w1);
        if (tid < (NVEC - 2560)) {  // 192 lanes
            fvec4 w2 = __builtin_nontemporal_load(&wrow[tid + 2560]);
            orow[tid + 2560] = q4(w2);
        }
    }
}

extern "C" void kernel_launch(void* const* d_in, const int* in_sizes, int n_in,
                              void* d_out, int out_size, void* d_ws, size_t ws_size,
                              hipStream_t stream) {
    const float* weight = (const float*)d_in[0];
    const float* alh    = (const float*)d_in[1];
    const float* bit    = (const float*)d_in[2];
    // d_in[3] = init_weight_bit (unused in forward at init)
    float* out = (float*)d_out;

    fake_quant_kernel<<<OUT_CH, 256, 0, stream>>>(weight, alh, bit, out);
}

// Round 3
// 295.600 us; speedup vs baseline: 1.0592x; 1.0159x over previous
//
#include <hip/hip_runtime.h>
#include <hip/hip_bf16.h>

#define OUT_CH 4096
#define IN_FEAT 11008
#define NVEC (IN_FEAT / 4)   // 2752 float4 per row
#define EPS 1e-5f
#define BIT_BOUND 6.0f

// Native clang vector type — accepted by __builtin_nontemporal_{load,store}
// (HIP's float4 is a struct and is rejected).
typedef float fvec4 __attribute__((ext_vector_type(4)));

// One block per output channel (row). Row scalars computed once per block.
//
// v4 = v1 (nt loads, nt stores, 294-297 us) with ONE change: all 10 full
// load batches are issued BEFORE any store.
//   Mechanism: vmcnt is a single in-order retirement FIFO covering loads
//   AND stores. In v1's 8->store8->2->store2 schedule, consuming the
//   batch-2 loads forces retirement of the 8 older nt stores first; nt
//   stores ack from the HBM write path (~hundreds of cycles), so every
//   wave serializes on store-drain mid-row. Hoisting all full loads ahead
//   of the first store removes that wait from the critical path.
//   (v2 bundled this with cached loads + launch_bounds(256,4) + 44-reg
//   branchless tail and regressed — the schedule was never isolated.)
// Tail (192 lanes, last 16B/lane) stays a trailing predicated load+store:
// its store-drain wait is paid once at the very end, negligible.
// Live data VGPRs: 10 x vec4 = 40, safely under the 64-VGPR occupancy cliff.
__global__ __launch_bounds__(256) void fake_quant_kernel(
    const float* __restrict__ weight,
    const float* __restrict__ alh,
    const float* __restrict__ bit,
    float* __restrict__ out)
{
    const int row = blockIdx.x;
    const int tid = threadIdx.x;

    const fvec4* __restrict__ wrow =
        (const fvec4*)(weight + (size_t)row * IN_FEAT);
    fvec4* __restrict__ orow = (fvec4*)(out + (size_t)row * IN_FEAT);

    // Issue all 10 full-batch loads first: covers vec4 indices 0..2559.
    fvec4 w[10];
    #pragma unroll
    for (int j = 0; j < 10; ++j)
        w[j] = __builtin_nontemporal_load(&wrow[tid + j * 256]);

    // Per-row quant params (forward values; STE affects only gradients).
    // Wave-uniform scalar loads; overlap with the vector loads above.
    const float s = fmaxf(alh[row], EPS);
    const float b_eff = fminf(fmaxf(fabsf(bit[row]), 1.0f), BIT_BOUND);
    const float b_r = rintf(b_eff);                        // jnp.round = half-to-even
    const float qmax = fmaxf(exp2f(b_r - 1.0f) - 1.0f, 1.0f);
    const float qmin = -qmax;

    // Exact IEEE division (matches np w/scale bit-exactly; rintf = half-even).
    auto q4 = [&](fvec4 v) -> fvec4 {
        fvec4 r;
        r.x = fminf(fmaxf(rintf(v.x / s), qmin), qmax) * s;
        r.y = fminf(fmaxf(rintf(v.y / s), qmin), qmax) * s;
        r.z = fminf(fmaxf(rintf(v.z / s), qmin), qmax) * s;
        r.w = fminf(fmaxf(rintf(v.w / s), qmin), qmax) * s;
        return r;
    };

    #pragma unroll
    for (int j = 0; j < 10; ++j)
        __builtin_nontemporal_store(q4(w[j]), &orow[tid + j * 256]);

    // Remainder: 2752 - 2560 = 192 lanes, one vec4 each.
    if (tid < (NVEC - 2560)) {
        fvec4 wt = __builtin_nontemporal_load(&wrow[tid + 2560]);
        __builtin_nontemporal_store(q4(wt), &orow[tid + 2560]);
    }
}

extern "C" void kernel_launch(void* const* d_in, const int* in_sizes, int n_in,
                              void* d_out, int out_size, void* d_ws, size_t ws_size,
                              hipStream_t stream) {
    const float* weight = (const float*)d_in[0];
    const float* alh    = (const float*)d_in[1];
    const float* bit    = (const float*)d_in[2];
    // d_in[3] = init_weight_bit (unused in forward at init)
    float* out = (float*)d_out;

    fake_quant_kernel<<<OUT_CH, 256, 0, stream>>>(weight, alh, bit, out);
}